// Round 1
// 458.468 us; speedup vs baseline: 1.0148x; 1.0148x over previous
//
#include <hip/hip_runtime.h>
#include <math.h>

typedef unsigned short u16;
typedef short s16x8 __attribute__((ext_vector_type(8)));
typedef float f32x4 __attribute__((ext_vector_type(4)));
typedef long long ll;

__device__ inline u16 f2bf(float f) {
    unsigned u = __float_as_uint(f);
    u += 0x7fffu + ((u >> 16) & 1u);
    return (u16)(u >> 16);
}
__device__ inline float bf2f(u16 h) { return __uint_as_float(((unsigned)h) << 16); }

// async global->LDS, 16B per lane; LDS dest = wave-uniform base + lane*16
__device__ __forceinline__ void glds16(const u16* g, u16* l) {
    __builtin_amdgcn_global_load_lds(
        (__attribute__((address_space(1))) void*)(void*)g,
        (__attribute__((address_space(3))) void*)l, 16, 0, 0);
}

// ---------------- LayerNorm -> bf16 (one block per row, D=1024) ----------------
__global__ __launch_bounds__(256) void ln_bf16(const float* __restrict__ x,
                                               const float* __restrict__ g,
                                               const float* __restrict__ b,
                                               u16* __restrict__ out, int D) {
    int row = blockIdx.x;
    const float* xr = x + (size_t)row * D;
    int t = threadIdx.x;
    float4 v = ((const float4*)xr)[t];
    float s = v.x + v.y + v.z + v.w;
    __shared__ float sm[4];
    #pragma unroll
    for (int o = 32; o > 0; o >>= 1) s += __shfl_down(s, o, 64);
    int lane = t & 63, wv = t >> 6;
    if (lane == 0) sm[wv] = s;
    __syncthreads();
    float mean = (sm[0] + sm[1] + sm[2] + sm[3]) * (1.0f / 1024.0f);
    float dx = v.x - mean, dy = v.y - mean, dz = v.z - mean, dw = v.w - mean;
    float s2 = dx * dx + dy * dy + dz * dz + dw * dw;
    __syncthreads();
    #pragma unroll
    for (int o = 32; o > 0; o >>= 1) s2 += __shfl_down(s2, o, 64);
    if (lane == 0) sm[wv] = s2;
    __syncthreads();
    float var = (sm[0] + sm[1] + sm[2] + sm[3]) * (1.0f / 1024.0f);
    float rstd = rsqrtf(var + 1e-5f);
    float4 gg = ((const float4*)g)[t], bb = ((const float4*)b)[t];
    ushort4 o4;
    o4.x = f2bf(dx * rstd * gg.x + bb.x);
    o4.y = f2bf(dy * rstd * gg.y + bb.y);
    o4.z = f2bf(dz * rstd * gg.z + bb.z);
    o4.w = f2bf(dw * rstd * gg.w + bb.w);
    ((ushort4*)(out + (size_t)row * D))[t] = o4;
}

// ---------------- combine split-K parts + residual + bias, then LayerNorm ----------------
__global__ __launch_bounds__(256) void combine_ln(
    const float* __restrict__ x, const float* __restrict__ p0,
    const float* __restrict__ p1, const float* __restrict__ ob,
    const float* __restrict__ g, const float* __restrict__ b,
    float* __restrict__ x2, u16* __restrict__ xn2) {
    int row = blockIdx.x;
    int t = threadIdx.x;
    size_t base = (size_t)row * 256;  // float4 units
    float4 v = ((const float4*)x)[base + t];
    float4 a0 = ((const float4*)p0)[base + t];
    float4 a1 = ((const float4*)p1)[base + t];
    float4 ob4 = ((const float4*)ob)[t];
    v.x += a0.x + a1.x + ob4.x;
    v.y += a0.y + a1.y + ob4.y;
    v.z += a0.z + a1.z + ob4.z;
    v.w += a0.w + a1.w + ob4.w;
    ((float4*)x2)[base + t] = v;
    float s = v.x + v.y + v.z + v.w;
    __shared__ float sm[4];
    #pragma unroll
    for (int o = 32; o > 0; o >>= 1) s += __shfl_down(s, o, 64);
    int lane = t & 63, wv = t >> 6;
    if (lane == 0) sm[wv] = s;
    __syncthreads();
    float mean = (sm[0] + sm[1] + sm[2] + sm[3]) * (1.0f / 1024.0f);
    float dx = v.x - mean, dy = v.y - mean, dz = v.z - mean, dw = v.w - mean;
    float s2 = dx * dx + dy * dy + dz * dz + dw * dw;
    __syncthreads();
    #pragma unroll
    for (int o = 32; o > 0; o >>= 1) s2 += __shfl_down(s2, o, 64);
    if (lane == 0) sm[wv] = s2;
    __syncthreads();
    float var = (sm[0] + sm[1] + sm[2] + sm[3]) * (1.0f / 1024.0f);
    float rstd = rsqrtf(var + 1e-5f);
    float4 gg = ((const float4*)g)[t], bb = ((const float4*)b)[t];
    ushort4 o4;
    o4.x = f2bf(dx * rstd * gg.x + bb.x);
    o4.y = f2bf(dy * rstd * gg.y + bb.y);
    o4.z = f2bf(dz * rstd * gg.z + bb.z);
    o4.w = f2bf(dw * rstd * gg.w + bb.w);
    ((ushort4*)(xn2 + (size_t)row * 1024))[t] = o4;
}

// out = x2 + p0 + p1 + b2
__global__ __launch_bounds__(256) void combine_out(
    const float* __restrict__ x2, const float* __restrict__ p0,
    const float* __restrict__ p1, const float* __restrict__ b2,
    float* __restrict__ out) {
    size_t i = (size_t)blockIdx.x * 256 + threadIdx.x;
    int col4 = (int)(i & 255);
    float4 v = ((const float4*)x2)[i];
    float4 a0 = ((const float4*)p0)[i];
    float4 a1 = ((const float4*)p1)[i];
    float4 bb = ((const float4*)b2)[col4];
    v.x += a0.x + a1.x + bb.x;
    v.y += a0.y + a1.y + bb.y;
    v.z += a0.z + a1.z + bb.z;
    v.w += a0.w + a1.w + bb.w;
    ((float4*)out)[i] = v;
}

// ---------------- prep: pack q_b,k_b,v_b -> bcat[3E]; zero den[BN] ----------------
__global__ void prep(const float* __restrict__ qb, const float* __restrict__ kb,
                     const float* __restrict__ vb, float* __restrict__ bcat,
                     float* __restrict__ den, int E, int BN) {
    int i = blockIdx.x * 256 + threadIdx.x;
    if (i < E) {
        bcat[i] = qb[i];
        bcat[E + i] = kb[i];
        bcat[2 * E + i] = vb[i];
    }
    if (i < BN) den[i] = 0.f;
}

// ---------------- all 6 weight transposes in one dispatch ----------------
__global__ __launch_bounds__(256) void transpose_all(
    const float* __restrict__ q_w, const float* __restrict__ k_w,
    const float* __restrict__ v_w, const float* __restrict__ o_w,
    const float* __restrict__ w1, const float* __restrict__ w2,
    u16* __restrict__ qkvT, u16* __restrict__ oT,
    u16* __restrict__ w1T, u16* __restrict__ w2T) {
    int z = blockIdx.y;
    const float* src;
    u16* dst;
    int R, C, tprLog;  // tiles-per-row = C/32, log2
    switch (z) {
        case 0: src = q_w; dst = qkvT;                           R = 1024; C = 2048; tprLog = 6; break;
        case 1: src = k_w; dst = qkvT + (size_t)2 * 1024 * 1024; R = 1024; C = 2048; tprLog = 6; break;
        case 2: src = v_w; dst = qkvT + (size_t)4 * 1024 * 1024; R = 1024; C = 2048; tprLog = 6; break;
        case 3: src = o_w; dst = oT;                             R = 2048; C = 1024; tprLog = 5; break;
        case 4: src = w1;  dst = w1T;                            R = 1024; C = 4096; tprLog = 7; break;
        default: src = w2; dst = w2T;                            R = 4096; C = 1024; tprLog = 5; break;
    }
    int bx = blockIdx.x;
    int ntiles = (R >> 5) << (tprLog);
    if (bx >= ntiles) return;
    int c0 = (bx & ((1 << tprLog) - 1)) * 32;
    int r0 = (bx >> tprLog) * 32;
    __shared__ u16 tile[32][33];
    int tx = threadIdx.x & 31, ty = threadIdx.x >> 5;
    #pragma unroll
    for (int i = 0; i < 32; i += 8)
        tile[ty + i][tx] = f2bf(src[(size_t)(r0 + ty + i) * C + c0 + tx]);
    __syncthreads();
    #pragma unroll
    for (int i = 0; i < 32; i += 8)
        dst[(size_t)(c0 + ty + i) * R + r0 + tx] = tile[tx][ty + i];
}

// generic bf16 transpose (used for V^T): in [R,C] (row stride ldIn) -> out [C,R]
__global__ __launch_bounds__(256) void transpose_u16(const u16* __restrict__ in,
                                                     u16* __restrict__ out,
                                                     int R, int C, int ldIn,
                                                     ll sIn, ll sOut) {
    in += (size_t)blockIdx.z * sIn;
    out += (size_t)blockIdx.z * sOut;
    __shared__ u16 tile[32][33];
    int tx = threadIdx.x & 31, ty = threadIdx.x >> 5;
    int c0 = blockIdx.x * 32, r0 = blockIdx.y * 32;
    #pragma unroll
    for (int i = 0; i < 32; i += 8)
        tile[ty + i][tx] = in[(size_t)(r0 + ty + i) * ldIn + c0 + tx];
    __syncthreads();
    #pragma unroll
    for (int i = 0; i < 32; i += 8)
        out[(size_t)(c0 + ty + i) * R + r0 + tx] = tile[tx][ty + i];
}

// ---------------- GEMM NT (128x128, 2-barrier) -- kept for TRIL/DIV/PART ----------------
enum { EPI_QKV = 0, EPI_TRIL = 2, EPI_DIV = 3, EPI_GELU = 5, EPI_PART = 6 };

#define TM 128
#define TN 128

template <int EPI, int BKt>
__global__ __launch_bounds__(256) void gemm_nt(
    const u16* __restrict__ A, const u16* __restrict__ B, void* __restrict__ Cv,
    const float* __restrict__ bias, float* __restrict__ den,
    int M, int N, int K, int lda, int ldb,
    ll sA, ll sB, ll sC, ll sAux) {
    int z = blockIdx.z;
    A += (size_t)z * sA;
    B += (size_t)z * sB;

    int p = blockIdx.y * gridDim.x + blockIdx.x;
    int m0, n0;
    if (EPI == EPI_TRIL || EPI == EPI_DIV) {
        int nb = gridDim.x;
        int panel = nb * 4;
        int pp = p / panel, rr = p - pp * panel;
        m0 = (pp * 4 + (rr & 3)) * TM;
        n0 = (rr >> 2) * TN;
    } else {
        int g = p & 7, r = p >> 3;
        int lw = gridDim.x >> 2, lh = gridDim.y >> 1;
        int ly = r / lw, lx = r - ly * lw;
        m0 = ((g >> 2) * lh + ly) * TM;
        n0 = ((g & 3) * lw + lx) * TN;
    }

    int t = threadIdx.x;

    if (EPI == EPI_TRIL && n0 > m0 + (TM - 1)) {
        u16* C = (u16*)Cv + (size_t)z * sC;
        #pragma unroll
        for (int s = 0; s < 8; ++s) {
            int v = t + 256 * s;
            int row = v >> 4, cf = (v & 15) * 8;
            *(uint4*)&C[(size_t)(m0 + row) * N + n0 + cf] = make_uint4(0, 0, 0, 0);
        }
        return;
    }

    __shared__ __align__(16) u16 As[TM * BKt];
    __shared__ __align__(16) u16 Bs[TN * BKt];

    f32x4 acc[4][4];
    #pragma unroll
    for (int i = 0; i < 4; i++)
        #pragma unroll
        for (int j = 0; j < 4; j++) { f32x4 zz = {0.f, 0.f, 0.f, 0.f}; acc[i][j] = zz; }

    int kend = (EPI == EPI_DIV) ? (m0 + TM < K ? m0 + TM : K) : K;

    int lane = t & 63, wv = t >> 6;
    int lr = lane & 15, q = lane >> 4;
    int wm = (wv & 1) * 64, wn = (wv >> 1) * 64;

    u16* lA = As + wv * 32 * BKt;
    u16* lB = Bs + wv * 32 * BKt;

    int srow, skf;
    if (BKt == 32) {
        srow = wv * 32 + (lane >> 2);
        skf = (((lane & 3) - ((lane >> 3) & 3)) & 3) * 8;
    } else {
        srow = wv * 32 + (lane >> 3);
        skf = (((lane & 7) - (lane >> 3)) & 7) * 8;
    }
    const u16* gA0 = A + (size_t)(m0 + srow) * lda + skf;
    const u16* gB0 = B + (size_t)(n0 + srow) * ldb + skf;

    int ca[2][4], cb[2][4];
    #pragma unroll
    for (int i = 0; i < 4; i++) {
        int ra = wm + i * 16 + lr;
        int rb = wn + i * 16 + lr;
        if (BKt == 32) {
            ca[0][i] = (ra * 4 + ((q + (ra >> 1)) & 3)) * 8;
            cb[0][i] = (rb * 4 + ((q + (rb >> 1)) & 3)) * 8;
        } else {
            ca[0][i] = (ra * 8 + ((q + (ra & 7)) & 7)) * 8;
            ca[1][i] = (ra * 8 + ((4 + q + (ra & 7)) & 7)) * 8;
            cb[0][i] = (rb * 8 + ((q + (rb & 7)) & 7)) * 8;
            cb[1][i] = (rb * 8 + ((4 + q + (rb & 7)) & 7)) * 8;
        }
    }

    for (int k0 = 0; k0 < kend; k0 += BKt) {
        if (BKt == 32) {
            glds16(gA0 + k0, lA);
            glds16(gA0 + k0 + (size_t)16 * lda, lA + 16 * BKt);
            glds16(gB0 + k0, lB);
            glds16(gB0 + k0 + (size_t)16 * ldb, lB + 16 * BKt);
        } else {
            #pragma unroll
            for (int r = 0; r < 4; ++r) {
                glds16(gA0 + k0 + (size_t)(8 * r) * lda, lA + r * 8 * BKt);
                glds16(gB0 + k0 + (size_t)(8 * r) * ldb, lB + r * 8 * BKt);
            }
        }
        __syncthreads();
        #pragma unroll
        for (int kk = 0; kk < BKt / 32; ++kk) {
            s16x8 af[4], bfr[4];
            #pragma unroll
            for (int i = 0; i < 4; i++) af[i] = *(const s16x8*)&As[ca[kk][i]];
            #pragma unroll
            for (int j = 0; j < 4; j++) bfr[j] = *(const s16x8*)&Bs[cb[kk][j]];
            #pragma unroll
            for (int i = 0; i < 4; i++)
                #pragma unroll
                for (int j = 0; j < 4; j++)
                    acc[i][j] = __builtin_amdgcn_mfma_f32_16x16x32_bf16(af[i], bfr[j], acc[i][j], 0, 0, 0);
        }
        __syncthreads();
    }

    u16* Cb = (u16*)Cv + (size_t)z * sC;
    float* Cf = (float*)Cv + (size_t)z * sC;
    bool isQK = (EPI == EPI_QKV) && (n0 < 4096);
    #pragma unroll
    for (int i = 0; i < 4; i++) {
        #pragma unroll
        for (int r = 0; r < 4; r++) {
            int row = m0 + wm + i * 16 + q * 4 + r;
            float rs = 0.f;
            #pragma unroll
            for (int j = 0; j < 4; j++) {
                int col = n0 + wn + j * 16 + lr;
                float v = acc[i][j][r];
                if (EPI == EPI_QKV) {
                    v += bias[col];
                    if (isQK) v = (v > 0.f) ? (v + 1.f) : __expf(v);
                    Cb[(size_t)row * N + col] = f2bf(v);
                } else if (EPI == EPI_TRIL) {
                    v = (col <= row) ? v : 0.f;
                    rs += v;
                    Cb[(size_t)row * N + col] = f2bf(v);
                } else if (EPI == EPI_DIV) {
                    float d = den[(size_t)z * sAux + row] + 1e-6f;
                    Cb[(size_t)row * N + col] = f2bf(v / d);
                } else if (EPI == EPI_GELU) {
                    v += bias[col];
                    float u = v * (0.7978845608f + 0.0356774081f * v * v);
                    u = fminf(u, 40.f);
                    float e = __expf(2.f * u);
                    v = v * __fdividef(e, e + 1.f);
                    Cb[(size_t)row * N + col] = f2bf(v);
                } else if (EPI == EPI_PART) {
                    Cf[(size_t)row * N + col] = v;
                }
            }
            if (EPI == EPI_TRIL) {
                #pragma unroll
                for (int m = 1; m < 16; m <<= 1) rs += __shfl_xor(rs, m, 16);
                if (lr == 0) atomicAdd(&den[(size_t)z * sAux + row], rs);
            }
        }
    }
}

// ---------------- GEMM NT 256x256, 8-wave, 8-phase counted-vmcnt schedule ----------------
// T3+T4+T5 per HK/m201 template. BK=64. LDS = 2 dbuf x 4 half-tiles
// (A0,A1,B0,B1; each 128x64 bf16 = 16KB) = 128 KB -> 1 block/CU, 8 waves.
// Each wave owns a 128x64 C tile: reads ONE A-half (phases 1,3) and ONE
// B-half (phases 1,2). Phases = C-quadrants (M0N0, M0N1, M1N1, M1N0).
// Staging: ph1->A1(t+1), ph2->B1(t+1), ph3->B0(t+2), ph4->A0(t+2); each
// issue lands after the barrier closing its region's last reader.
// One vmcnt(4) per K-tile (2 half-tiles = 4 load-instrs in flight) retires
// all of tile t+1 before its first ds_read. Tail: clamp staged k-tile
// (re-reads last tile; region no longer live; L2-hot).
// LDS layout per half-tile identical to gemm_nt BK=64 (16B-chunk swizzle:
// global chunk c of row r stored at position (c+r)&7) -> conflict-free.
template <int EPI>
__global__ __launch_bounds__(512, 2) void gemm_nt256(
    const u16* __restrict__ A, const u16* __restrict__ B, u16* __restrict__ C,
    const float* __restrict__ bias, int M, int N, int K, int lda, int ldb) {

    __shared__ __align__(16) u16 lds[2][4][128 * 64];

    // per-XCD rectangular chunk (gx%4==0, gy%2==0 for our launches)
    int p = blockIdx.y * gridDim.x + blockIdx.x;
    int g = p & 7, rr = p >> 3;
    int lw = gridDim.x >> 2, lh = gridDim.y >> 1;
    int ly = rr / lw, lx = rr - ly * lw;
    int m0 = ((g >> 2) * lh + ly) * 256;
    int n0 = ((g & 3) * lw + lx) * 256;

    int t = threadIdx.x;
    int lane = t & 63, wid = t >> 6;
    int lr = lane & 15, q = lane >> 4;

    // staging: per half-tile, wave w loads rows [w*16, w*16+16) in 2 issues
    int sr = wid * 16 + (lane >> 3);
    int skf = (((lane & 7) - (lane >> 3)) & 7) * 8;  // pre-swizzled source chunk
    const u16* gA = A + (size_t)(m0 + sr) * lda + skf;
    const u16* gB = B + (size_t)(n0 + sr) * ldb + skf;
    int sd = wid * 1024;  // u16 offset of this wave's 1KB chunk pair

    int nk = K >> 6;

    auto stage = [&](int half, int tt, int d) {
        int kt = tt < nk ? tt : nk - 1;  // branchless tail (redundant re-read)
        const u16* s = (half < 2 ? gA + (size_t)(half * 128) * lda
                                 : gB + (size_t)((half - 2) * 128) * ldb) + kt * 64;
        size_t ld = (half < 2) ? (size_t)lda : (size_t)ldb;
        glds16(s, &lds[d][half][sd]);
        glds16(s + 8 * ld, &lds[d][half][sd + 512]);
    };

    f32x4 acc[8][4];
    #pragma unroll
    for (int i = 0; i < 8; i++)
        #pragma unroll
        for (int j = 0; j < 4; j++) { f32x4 zz = {0.f, 0.f, 0.f, 0.f}; acc[i][j] = zz; }

    int ha = wid >> 2;         // which A half this wave reads
    int hb = (wid >> 1) & 1;   // which B half
    // variable part of fragment read offsets (static part folds into ds imm)
    int vb0 = lr * 64 + (((q + lr) & 7) << 3);       // kk=0
    int vb1 = lr * 64 + (((4 + q + lr) & 7) << 3);   // kk=1
    int bb = (wid & 1) * 4096;  // 64-row offset within B half

    // ---- prologue: tile 0 complete + B0,A0 of tile 1 in flight ----
    stage(0, 0, 0); stage(1, 0, 0); stage(2, 0, 0); stage(3, 0, 0);
    stage(2, 1, 1); stage(0, 1, 1);
    asm volatile("s_waitcnt vmcnt(4)" ::: "memory");
    asm volatile("s_barrier" ::: "memory");

    s16x8 a[4][2], b0[2][2], b1[2][2];

    for (int tt = 0; tt < nk; ++tt) {
        int cur = tt & 1, nxt = cur ^ 1;
        const u16* Ah = &lds[cur][ha][0];
        const u16* Bh = &lds[cur][2 + hb][bb];

        // ---- phase 1: ds A-M0 + B-N0 | stage A1(t+1) | mfma (M0,N0) ----
        #pragma unroll
        for (int i = 0; i < 4; i++) {
            a[i][0] = *(const s16x8*)&Ah[vb0 + i * 1024];
            a[i][1] = *(const s16x8*)&Ah[vb1 + i * 1024];
        }
        #pragma unroll
        for (int j = 0; j < 2; j++) {
            b0[j][0] = *(const s16x8*)&Bh[vb0 + j * 1024];
            b0[j][1] = *(const s16x8*)&Bh[vb1 + j * 1024];
        }
        stage(1, tt + 1, nxt);
        asm volatile("s_barrier" ::: "memory");
        asm volatile("s_waitcnt lgkmcnt(0)" ::: "memory");
        __builtin_amdgcn_s_setprio(1);
        #pragma unroll
        for (int i = 0; i < 4; i++)
            #pragma unroll
            for (int j = 0; j < 2; j++) {
                acc[i][j] = __builtin_amdgcn_mfma_f32_16x16x32_bf16(a[i][0], b0[j][0], acc[i][j], 0, 0, 0);
                acc[i][j] = __builtin_amdgcn_mfma_f32_16x16x32_bf16(a[i][1], b0[j][1], acc[i][j], 0, 0, 0);
            }
        __builtin_amdgcn_s_setprio(0);
        asm volatile("s_barrier" ::: "memory");

        // ---- phase 2: ds B-N1 | stage B1(t+1) | mfma (M0,N1) ----
        #pragma unroll
        for (int j = 0; j < 2; j++) {
            b1[j][0] = *(const s16x8*)&Bh[2048 + vb0 + j * 1024];
            b1[j][1] = *(const s16x8*)&Bh[2048 + vb1 + j * 1024];
        }
        stage(3, tt + 1, nxt);
        asm volatile("s_barrier" ::: "memory");
        asm volatile("s_waitcnt lgkmcnt(0)" ::: "memory");
        __builtin_amdgcn_s_setprio(1);
        #pragma unroll
        for (int i = 0; i < 4; i++)
            #pragma unroll
            for (int j = 0; j < 2; j++) {
                acc[i][2 + j] = __builtin_amdgcn_mfma_f32_16x16x32_bf16(a[i][0], b1[j][0], acc[i][2 + j], 0, 0, 0);
                acc[i][2 + j] = __builtin_amdgcn_mfma_f32_16x16x32_bf16(a[i][1], b1[j][1], acc[i][2 + j], 0, 0, 0);
            }
        __builtin_amdgcn_s_setprio(0);
        asm volatile("s_barrier" ::: "memory");

        // ---- phase 3: ds A-M1 | stage B0(t+2) | mfma (M1,N1) ----
        #pragma unroll
        for (int i = 0; i < 4; i++) {
            a[i][0] = *(const s16x8*)&Ah[4096 + vb0 + i * 1024];
            a[i][1] = *(const s16x8*)&Ah[4096 + vb1 + i * 1024];
        }
        stage(2, tt + 2, cur);
        asm volatile("s_barrier" ::: "memory");
        asm volatile("s_waitcnt lgkmcnt(0)" ::: "memory");
        __builtin_amdgcn_s_setprio(1);
        #pragma unroll
        for (int i = 0; i < 4; i++)
            #pragma unroll
            for (int j = 0; j < 2; j++) {
                acc[4 + i][2 + j] = __builtin_amdgcn_mfma_f32_16x16x32_bf16(a[i][0], b1[j][0], acc[4 + i][2 + j], 0, 0, 0);
                acc[4 + i][2 + j] = __builtin_amdgcn_mfma_f32_16x16x32_bf16(a[i][1], b1[j][1], acc[4 + i][2 + j], 0, 0, 0);
            }
        __builtin_amdgcn_s_setprio(0);
        asm volatile("s_barrier" ::: "memory");

        // ---- phase 4: stage A0(t+2) | mfma (M1,N0) | vmcnt(4) ----
        stage(0, tt + 2, cur);
        asm volatile("s_barrier" ::: "memory");
        __builtin_amdgcn_s_setprio(1);
        #pragma unroll
        for (int i = 0; i < 4; i++)
            #pragma unroll
            for (int j = 0; j < 2; j++) {
                acc[4 + i][j] = __builtin_amdgcn_mfma_f32_16x16x32_bf16(a[i][0], b0[j][0], acc[4 + i][j], 0, 0, 0);
                acc[4 + i][j] = __builtin_amdgcn_mfma_f32_16x16x32_bf16(a[i][1], b0[j][1], acc[4 + i][j], 0, 0, 0);
            }
        __builtin_amdgcn_s_setprio(0);
        asm volatile("s_waitcnt vmcnt(4)" ::: "memory");  // tile t+1 landed; never 0
        asm volatile("s_barrier" ::: "memory");
    }

    asm volatile("s_waitcnt vmcnt(0)" ::: "memory");  // drain DMA before LDS dealloc

    // ---- epilogue ----
    int wm = (wid >> 2) * 128, wn = (wid & 3) * 64;
    #pragma unroll
    for (int mi = 0; mi < 8; mi++) {
        #pragma unroll
        for (int r = 0; r < 4; r++) {
            int row = m0 + wm + mi * 16 + q * 4 + r;
            #pragma unroll
            for (int nj = 0; nj < 4; nj++) {
                int col = n0 + wn + nj * 16 + lr;
                float v = acc[mi][nj][r] + bias[col];
                if (EPI == EPI_QKV) {
                    if (n0 + wn + nj * 16 < 4096) v = (v > 0.f) ? (v + 1.f) : __expf(v);  // elu+1 on Q,K
                } else {  // EPI_GELU
                    float u = v * (0.7978845608f + 0.0356774081f * v * v);
                    u = fminf(u, 40.f);
                    float e = __expf(2.f * u);
                    v = v * __fdividef(e, e + 1.f);
                }
                C[(size_t)row * N + col] = f2bf(v);
            }
        }
    }
}

extern "C" void kernel_launch(void* const* d_in, const int* in_sizes, int n_in,
                              void* d_out, int out_size, void* d_ws, size_t ws_size,
                              hipStream_t stream) {
    const float* x    = (const float*)d_in[0];
    const float* q_w  = (const float*)d_in[1];
    const float* q_b  = (const float*)d_in[2];
    const float* k_w  = (const float*)d_in[3];
    const float* k_b  = (const float*)d_in[4];
    const float* v_w  = (const float*)d_in[5];
    const float* v_b  = (const float*)d_in[6];
    const float* o_w  = (const float*)d_in[7];
    const float* o_b  = (const float*)d_in[8];
    const float* ln1g = (const float*)d_in[9];
    const float* ln1b = (const float*)d_in[10];
    const float* ln2g = (const float*)d_in[11];
    const float* ln2b = (const float*)d_in[12];
    const float* w1   = (const float*)d_in[13];
    const float* b1   = (const float*)d_in[14];
    const float* w2   = (const float*)d_in[15];
    const float* b2   = (const float*)d_in[16];
    float* out = (float*)d_out;

    constexpr int Bb = 2, N = 2048, D = 1024, E = 2048, F = 4096;
    constexpr int BN = Bb * N;     // 4096
    constexpr int E3 = 3 * E;      // 6144

    char* ws = (char*)d_ws;
    size_t off = 0;
    auto alloc = [&](size_t bytes) -> void* {
        void* p = ws + off;
        off += (bytes + 255) & ~(size_t)255;
        return p;
    };
    u16*   qkvT = (u16*)alloc((size_t)E3 * D * 2);     // 12 MB
    u16*   oT   = (u16*)alloc((size_t)D * E * 2);      // 4 MB
    u16*   w1T  = (u16*)alloc((size_t)F * D * 2);      // 8 MB
    u16*   w2T  = (u16*)alloc((size_t)D * F * 2);      // 8 MB
    float* bcat = (float*)alloc((size_t)E3 * 4);
    u16*   xn   = (u16*)alloc((size_t)BN * D * 2);     // 8 MB (reused as xn2)
    u16*   QKV  = (u16*)alloc((size_t)BN * E3 * 2);    // 48 MB (reused: P, h)
    u16*   Vt   = (u16*)alloc((size_t)Bb * E * N * 2); // 16 MB (reused as x2 fp32)
    u16*   Amat = (u16*)alloc((size_t)Bb * N * N * 2); // 32 MB (reused as parts)
    float* den  = (float*)alloc((size_t)BN * 4);

    u16*   xn2 = xn;
    u16*   P   = QKV;                  // [BN,E] bf16
    u16*   h   = QKV + (size_t)8 * 1024 * 1024;  // [BN,F] bf16
    float* x2  = (float*)Vt;           // [BN,D] fp32
    float* pt0 = (float*)Amat;         // split-K partial 0
    float* pt1 = pt0 + (size_t)BN * D; // split-K partial 1

    dim3 blk(256);

    // ---- prep: biases + den zero ----
    prep<<<dim3((BN + 255) / 256), blk, 0, stream>>>(q_b, k_b, v_b, bcat, den, E, BN);

    // ---- all weight transposes, one dispatch ----
    transpose_all<<<dim3(4096, 6), blk, 0, stream>>>(
        q_w, k_w, v_w, o_w, w1, w2, qkvT, oT, w1T, w2T);

    // ---- LN1 ----
    ln_bf16<<<BN, blk, 0, stream>>>(x, ln1g, ln1b, xn, D);

    // ---- fused QKV projection: [BN,3E], elu+1 on Q,K cols (256^2 8-phase) ----
    gemm_nt256<EPI_QKV><<<dim3(E3 / 256, BN / 256), dim3(512), 0, stream>>>(
        xn, qkvT, QKV, bcat, BN, E3, D, D, D);

    // ---- V^T per batch: [N,E] (stride 3E) -> [E,N] ----
    transpose_u16<<<dim3(E / 32, N / 32, Bb), blk, 0, stream>>>(
        QKV + 2 * E, Vt, N, E, E3, (ll)N * E3, (ll)E * N);

    // ---- A = tril(Q K^T) per batch, fused rowsum -> den (BK=64) ----
    gemm_nt<EPI_TRIL, 64><<<dim3(N / 128, N / 128, Bb), blk, 0, stream>>>(
        QKV, QKV + E, Amat, nullptr, den, N, N, E, E3, E3,
        (ll)N * E3, (ll)N * E3, (ll)N * N, (ll)N);

    // ---- P = (A @ V) / den (triangular K-loop, BK=64) ----
    gemm_nt<EPI_DIV, 64><<<dim3(E / 128, N / 128, Bb), blk, 0, stream>>>(
        Amat, Vt, P, nullptr, den, N, E, N, N, N,
        (ll)N * N, (ll)E * N, (ll)N * E, (ll)N);

    // ---- split-K=2: parts = P @ o_w (fp32), BK=64 ----
    gemm_nt<EPI_PART, 64><<<dim3(D / 128, BN / 128, 2), blk, 0, stream>>>(
        P, oT, pt0, nullptr, nullptr, BN, D, E / 2, E, E,
        (ll)(E / 2), (ll)(E / 2), (ll)BN * D, 0);

    // ---- x2 = x + p0 + p1 + o_b ; xn2 = LN2(x2) ----
    combine_ln<<<BN, blk, 0, stream>>>(x, pt0, pt1, o_b, ln2g, ln2b, x2, xn2);

    // ---- h = gelu(xn2 @ w1 + b1) (256^2 8-phase) ----
    gemm_nt256<EPI_GELU><<<dim3(F / 256, BN / 256), dim3(512), 0, stream>>>(
        xn2, w1T, h, b1, BN, F, D, D, D);

    // ---- split-K=2: parts = h @ w2 (fp32), BK=64 ----
    gemm_nt<EPI_PART, 64><<<dim3(D / 128, BN / 128, 2), blk, 0, stream>>>(
        h, w2T, pt0, nullptr, nullptr, BN, D, F / 2, F, F,
        (ll)(F / 2), (ll)(F / 2), (ll)BN * D, 0);

    // ---- out = x2 + p0 + p1 + b2 ----
    combine_out<<<dim3(BN * D / 4 / 256), blk, 0, stream>>>(x2, pt0, pt1, b2, out);
}

// Round 2
// 446.501 us; speedup vs baseline: 1.0420x; 1.0268x over previous
//
#include <hip/hip_runtime.h>
#include <math.h>

typedef unsigned short u16;
typedef short s16x8 __attribute__((ext_vector_type(8)));
typedef float f32x4 __attribute__((ext_vector_type(4)));
typedef long long ll;

__device__ inline u16 f2bf(float f) {
    unsigned u = __float_as_uint(f);
    u += 0x7fffu + ((u >> 16) & 1u);
    return (u16)(u >> 16);
}
__device__ inline float bf2f(u16 h) { return __uint_as_float(((unsigned)h) << 16); }

// async global->LDS, 16B per lane; LDS dest = wave-uniform base + lane*16
__device__ __forceinline__ void glds16(const u16* g, u16* l) {
    __builtin_amdgcn_global_load_lds(
        (__attribute__((address_space(1))) void*)(void*)g,
        (__attribute__((address_space(3))) void*)l, 16, 0, 0);
}

// ---------------- LayerNorm -> bf16 (one block per row, D=1024) ----------------
__global__ __launch_bounds__(256) void ln_bf16(const float* __restrict__ x,
                                               const float* __restrict__ g,
                                               const float* __restrict__ b,
                                               u16* __restrict__ out, int D) {
    int row = blockIdx.x;
    const float* xr = x + (size_t)row * D;
    int t = threadIdx.x;
    float4 v = ((const float4*)xr)[t];
    float s = v.x + v.y + v.z + v.w;
    __shared__ float sm[4];
    #pragma unroll
    for (int o = 32; o > 0; o >>= 1) s += __shfl_down(s, o, 64);
    int lane = t & 63, wv = t >> 6;
    if (lane == 0) sm[wv] = s;
    __syncthreads();
    float mean = (sm[0] + sm[1] + sm[2] + sm[3]) * (1.0f / 1024.0f);
    float dx = v.x - mean, dy = v.y - mean, dz = v.z - mean, dw = v.w - mean;
    float s2 = dx * dx + dy * dy + dz * dz + dw * dw;
    __syncthreads();
    #pragma unroll
    for (int o = 32; o > 0; o >>= 1) s2 += __shfl_down(s2, o, 64);
    if (lane == 0) sm[wv] = s2;
    __syncthreads();
    float var = (sm[0] + sm[1] + sm[2] + sm[3]) * (1.0f / 1024.0f);
    float rstd = rsqrtf(var + 1e-5f);
    float4 gg = ((const float4*)g)[t], bb = ((const float4*)b)[t];
    ushort4 o4;
    o4.x = f2bf(dx * rstd * gg.x + bb.x);
    o4.y = f2bf(dy * rstd * gg.y + bb.y);
    o4.z = f2bf(dz * rstd * gg.z + bb.z);
    o4.w = f2bf(dw * rstd * gg.w + bb.w);
    ((ushort4*)(out + (size_t)row * D))[t] = o4;
}

// ---------------- combine split-K parts + residual + bias, then LayerNorm ----------------
__global__ __launch_bounds__(256) void combine_ln(
    const float* __restrict__ x, const float* __restrict__ p0,
    const float* __restrict__ p1, const float* __restrict__ ob,
    const float* __restrict__ g, const float* __restrict__ b,
    float* __restrict__ x2, u16* __restrict__ xn2) {
    int row = blockIdx.x;
    int t = threadIdx.x;
    size_t base = (size_t)row * 256;  // float4 units
    float4 v = ((const float4*)x)[base + t];
    float4 a0 = ((const float4*)p0)[base + t];
    float4 a1 = ((const float4*)p1)[base + t];
    float4 ob4 = ((const float4*)ob)[t];
    v.x += a0.x + a1.x + ob4.x;
    v.y += a0.y + a1.y + ob4.y;
    v.z += a0.z + a1.z + ob4.z;
    v.w += a0.w + a1.w + ob4.w;
    ((float4*)x2)[base + t] = v;
    float s = v.x + v.y + v.z + v.w;
    __shared__ float sm[4];
    #pragma unroll
    for (int o = 32; o > 0; o >>= 1) s += __shfl_down(s, o, 64);
    int lane = t & 63, wv = t >> 6;
    if (lane == 0) sm[wv] = s;
    __syncthreads();
    float mean = (sm[0] + sm[1] + sm[2] + sm[3]) * (1.0f / 1024.0f);
    float dx = v.x - mean, dy = v.y - mean, dz = v.z - mean, dw = v.w - mean;
    float s2 = dx * dx + dy * dy + dz * dz + dw * dw;
    __syncthreads();
    #pragma unroll
    for (int o = 32; o > 0; o >>= 1) s2 += __shfl_down(s2, o, 64);
    if (lane == 0) sm[wv] = s2;
    __syncthreads();
    float var = (sm[0] + sm[1] + sm[2] + sm[3]) * (1.0f / 1024.0f);
    float rstd = rsqrtf(var + 1e-5f);
    float4 gg = ((const float4*)g)[t], bb = ((const float4*)b)[t];
    ushort4 o4;
    o4.x = f2bf(dx * rstd * gg.x + bb.x);
    o4.y = f2bf(dy * rstd * gg.y + bb.y);
    o4.z = f2bf(dz * rstd * gg.z + bb.z);
    o4.w = f2bf(dw * rstd * gg.w + bb.w);
    ((ushort4*)(xn2 + (size_t)row * 1024))[t] = o4;
}

// out = x2 + p0 + p1 + b2
__global__ __launch_bounds__(256) void combine_out(
    const float* __restrict__ x2, const float* __restrict__ p0,
    const float* __restrict__ p1, const float* __restrict__ b2,
    float* __restrict__ out) {
    size_t i = (size_t)blockIdx.x * 256 + threadIdx.x;
    int col4 = (int)(i & 255);
    float4 v = ((const float4*)x2)[i];
    float4 a0 = ((const float4*)p0)[i];
    float4 a1 = ((const float4*)p1)[i];
    float4 bb = ((const float4*)b2)[col4];
    v.x += a0.x + a1.x + bb.x;
    v.y += a0.y + a1.y + bb.y;
    v.z += a0.z + a1.z + bb.z;
    v.w += a0.w + a1.w + bb.w;
    ((float4*)out)[i] = v;
}

// ---------------- prep: pack q_b,k_b,v_b -> bcat[3E]; zero den[BN] ----------------
__global__ void prep(const float* __restrict__ qb, const float* __restrict__ kb,
                     const float* __restrict__ vb, float* __restrict__ bcat,
                     float* __restrict__ den, int E, int BN) {
    int i = blockIdx.x * 256 + threadIdx.x;
    if (i < E) {
        bcat[i] = qb[i];
        bcat[E + i] = kb[i];
        bcat[2 * E + i] = vb[i];
    }
    if (i < BN) den[i] = 0.f;
}

// ---------------- all 6 weight transposes in one dispatch ----------------
__global__ __launch_bounds__(256) void transpose_all(
    const float* __restrict__ q_w, const float* __restrict__ k_w,
    const float* __restrict__ v_w, const float* __restrict__ o_w,
    const float* __restrict__ w1, const float* __restrict__ w2,
    u16* __restrict__ qkvT, u16* __restrict__ oT,
    u16* __restrict__ w1T, u16* __restrict__ w2T) {
    int z = blockIdx.y;
    const float* src;
    u16* dst;
    int R, C, tprLog;  // tiles-per-row = C/32, log2
    switch (z) {
        case 0: src = q_w; dst = qkvT;                           R = 1024; C = 2048; tprLog = 6; break;
        case 1: src = k_w; dst = qkvT + (size_t)2 * 1024 * 1024; R = 1024; C = 2048; tprLog = 6; break;
        case 2: src = v_w; dst = qkvT + (size_t)4 * 1024 * 1024; R = 1024; C = 2048; tprLog = 6; break;
        case 3: src = o_w; dst = oT;                             R = 2048; C = 1024; tprLog = 5; break;
        case 4: src = w1;  dst = w1T;                            R = 1024; C = 4096; tprLog = 7; break;
        default: src = w2; dst = w2T;                            R = 4096; C = 1024; tprLog = 5; break;
    }
    int bx = blockIdx.x;
    int ntiles = (R >> 5) << (tprLog);
    if (bx >= ntiles) return;
    int c0 = (bx & ((1 << tprLog) - 1)) * 32;
    int r0 = (bx >> tprLog) * 32;
    __shared__ u16 tile[32][33];
    int tx = threadIdx.x & 31, ty = threadIdx.x >> 5;
    #pragma unroll
    for (int i = 0; i < 32; i += 8)
        tile[ty + i][tx] = f2bf(src[(size_t)(r0 + ty + i) * C + c0 + tx]);
    __syncthreads();
    #pragma unroll
    for (int i = 0; i < 32; i += 8)
        dst[(size_t)(c0 + ty + i) * R + r0 + tx] = tile[tx][ty + i];
}

// generic bf16 transpose (used for V^T): in [R,C] (row stride ldIn) -> out [C,R]
__global__ __launch_bounds__(256) void transpose_u16(const u16* __restrict__ in,
                                                     u16* __restrict__ out,
                                                     int R, int C, int ldIn,
                                                     ll sIn, ll sOut) {
    in += (size_t)blockIdx.z * sIn;
    out += (size_t)blockIdx.z * sOut;
    __shared__ u16 tile[32][33];
    int tx = threadIdx.x & 31, ty = threadIdx.x >> 5;
    int c0 = blockIdx.x * 32, r0 = blockIdx.y * 32;
    #pragma unroll
    for (int i = 0; i < 32; i += 8)
        tile[ty + i][tx] = in[(size_t)(r0 + ty + i) * ldIn + c0 + tx];
    __syncthreads();
    #pragma unroll
    for (int i = 0; i < 32; i += 8)
        out[(size_t)(c0 + ty + i) * R + r0 + tx] = tile[tx][ty + i];
}

// ---------------- GEMM NT (128x128, 2-barrier) -- kept for TRIL/DIV/PART ----------------
enum { EPI_QKV = 0, EPI_TRIL = 2, EPI_DIV = 3, EPI_GELU = 5, EPI_PART = 6 };

#define TM 128
#define TN 128

template <int EPI, int BKt>
__global__ __launch_bounds__(256) void gemm_nt(
    const u16* __restrict__ A, const u16* __restrict__ B, void* __restrict__ Cv,
    const float* __restrict__ bias, float* __restrict__ den,
    int M, int N, int K, int lda, int ldb,
    ll sA, ll sB, ll sC, ll sAux) {
    int z = blockIdx.z;
    A += (size_t)z * sA;
    B += (size_t)z * sB;

    int p = blockIdx.y * gridDim.x + blockIdx.x;
    int m0, n0;
    if (EPI == EPI_TRIL || EPI == EPI_DIV) {
        int nb = gridDim.x;
        int panel = nb * 4;
        int pp = p / panel, rr = p - pp * panel;
        m0 = (pp * 4 + (rr & 3)) * TM;
        n0 = (rr >> 2) * TN;
    } else {
        int g = p & 7, r = p >> 3;
        int lw = gridDim.x >> 2, lh = gridDim.y >> 1;
        int ly = r / lw, lx = r - ly * lw;
        m0 = ((g >> 2) * lh + ly) * TM;
        n0 = ((g & 3) * lw + lx) * TN;
    }

    int t = threadIdx.x;

    if (EPI == EPI_TRIL && n0 > m0 + (TM - 1)) {
        u16* C = (u16*)Cv + (size_t)z * sC;
        #pragma unroll
        for (int s = 0; s < 8; ++s) {
            int v = t + 256 * s;
            int row = v >> 4, cf = (v & 15) * 8;
            *(uint4*)&C[(size_t)(m0 + row) * N + n0 + cf] = make_uint4(0, 0, 0, 0);
        }
        return;
    }

    __shared__ __align__(16) u16 As[TM * BKt];
    __shared__ __align__(16) u16 Bs[TN * BKt];

    f32x4 acc[4][4];
    #pragma unroll
    for (int i = 0; i < 4; i++)
        #pragma unroll
        for (int j = 0; j < 4; j++) { f32x4 zz = {0.f, 0.f, 0.f, 0.f}; acc[i][j] = zz; }

    int kend = (EPI == EPI_DIV) ? (m0 + TM < K ? m0 + TM : K) : K;

    int lane = t & 63, wv = t >> 6;
    int lr = lane & 15, q = lane >> 4;
    int wm = (wv & 1) * 64, wn = (wv >> 1) * 64;

    u16* lA = As + wv * 32 * BKt;
    u16* lB = Bs + wv * 32 * BKt;

    int srow, skf;
    if (BKt == 32) {
        srow = wv * 32 + (lane >> 2);
        skf = (((lane & 3) - ((lane >> 3) & 3)) & 3) * 8;
    } else {
        srow = wv * 32 + (lane >> 3);
        skf = (((lane & 7) - (lane >> 3)) & 7) * 8;
    }
    const u16* gA0 = A + (size_t)(m0 + srow) * lda + skf;
    const u16* gB0 = B + (size_t)(n0 + srow) * ldb + skf;

    int ca[2][4], cb[2][4];
    #pragma unroll
    for (int i = 0; i < 4; i++) {
        int ra = wm + i * 16 + lr;
        int rb = wn + i * 16 + lr;
        if (BKt == 32) {
            ca[0][i] = (ra * 4 + ((q + (ra >> 1)) & 3)) * 8;
            cb[0][i] = (rb * 4 + ((q + (rb >> 1)) & 3)) * 8;
        } else {
            ca[0][i] = (ra * 8 + ((q + (ra & 7)) & 7)) * 8;
            ca[1][i] = (ra * 8 + ((4 + q + (ra & 7)) & 7)) * 8;
            cb[0][i] = (rb * 8 + ((q + (rb & 7)) & 7)) * 8;
            cb[1][i] = (rb * 8 + ((4 + q + (rb & 7)) & 7)) * 8;
        }
    }

    for (int k0 = 0; k0 < kend; k0 += BKt) {
        if (BKt == 32) {
            glds16(gA0 + k0, lA);
            glds16(gA0 + k0 + (size_t)16 * lda, lA + 16 * BKt);
            glds16(gB0 + k0, lB);
            glds16(gB0 + k0 + (size_t)16 * ldb, lB + 16 * BKt);
        } else {
            #pragma unroll
            for (int r = 0; r < 4; ++r) {
                glds16(gA0 + k0 + (size_t)(8 * r) * lda, lA + r * 8 * BKt);
                glds16(gB0 + k0 + (size_t)(8 * r) * ldb, lB + r * 8 * BKt);
            }
        }
        __syncthreads();
        #pragma unroll
        for (int kk = 0; kk < BKt / 32; ++kk) {
            s16x8 af[4], bfr[4];
            #pragma unroll
            for (int i = 0; i < 4; i++) af[i] = *(const s16x8*)&As[ca[kk][i]];
            #pragma unroll
            for (int j = 0; j < 4; j++) bfr[j] = *(const s16x8*)&Bs[cb[kk][j]];
            #pragma unroll
            for (int i = 0; i < 4; i++)
                #pragma unroll
                for (int j = 0; j < 4; j++)
                    acc[i][j] = __builtin_amdgcn_mfma_f32_16x16x32_bf16(af[i], bfr[j], acc[i][j], 0, 0, 0);
        }
        __syncthreads();
    }

    u16* Cb = (u16*)Cv + (size_t)z * sC;
    float* Cf = (float*)Cv + (size_t)z * sC;
    bool isQK = (EPI == EPI_QKV) && (n0 < 4096);
    #pragma unroll
    for (int i = 0; i < 4; i++) {
        #pragma unroll
        for (int r = 0; r < 4; r++) {
            int row = m0 + wm + i * 16 + q * 4 + r;
            float rs = 0.f;
            #pragma unroll
            for (int j = 0; j < 4; j++) {
                int col = n0 + wn + j * 16 + lr;
                float v = acc[i][j][r];
                if (EPI == EPI_QKV) {
                    v += bias[col];
                    if (isQK) v = (v > 0.f) ? (v + 1.f) : __expf(v);
                    Cb[(size_t)row * N + col] = f2bf(v);
                } else if (EPI == EPI_TRIL) {
                    v = (col <= row) ? v : 0.f;
                    rs += v;
                    Cb[(size_t)row * N + col] = f2bf(v);
                } else if (EPI == EPI_DIV) {
                    float d = den[(size_t)z * sAux + row] + 1e-6f;
                    Cb[(size_t)row * N + col] = f2bf(v / d);
                } else if (EPI == EPI_GELU) {
                    v += bias[col];
                    float u = v * (0.7978845608f + 0.0356774081f * v * v);
                    u = fminf(u, 40.f);
                    float e = __expf(2.f * u);
                    v = v * __fdividef(e, e + 1.f);
                    Cb[(size_t)row * N + col] = f2bf(v);
                } else if (EPI == EPI_PART) {
                    Cf[(size_t)row * N + col] = v;
                }
            }
            if (EPI == EPI_TRIL) {
                #pragma unroll
                for (int m = 1; m < 16; m <<= 1) rs += __shfl_xor(rs, m, 16);
                if (lr == 0) atomicAdd(&den[(size_t)z * sAux + row], rs);
            }
        }
    }
}

// ---------------- GEMM NT 256x256, 8-wave, 4-phase counted-vmcnt (kept for GELU A/B) ----------------
template <int EPI>
__global__ __launch_bounds__(512, 2) void gemm_nt256(
    const u16* __restrict__ A, const u16* __restrict__ B, u16* __restrict__ C,
    const float* __restrict__ bias, int M, int N, int K, int lda, int ldb) {

    __shared__ __align__(16) u16 lds[2][4][128 * 64];

    int p = blockIdx.y * gridDim.x + blockIdx.x;
    int g = p & 7, rr = p >> 3;
    int lw = gridDim.x >> 2, lh = gridDim.y >> 1;
    int ly = rr / lw, lx = rr - ly * lw;
    int m0 = ((g >> 2) * lh + ly) * 256;
    int n0 = ((g & 3) * lw + lx) * 256;

    int t = threadIdx.x;
    int lane = t & 63, wid = t >> 6;
    int lr = lane & 15, q = lane >> 4;

    int sr = wid * 16 + (lane >> 3);
    int skf = (((lane & 7) - (lane >> 3)) & 7) * 8;
    const u16* gA = A + (size_t)(m0 + sr) * lda + skf;
    const u16* gB = B + (size_t)(n0 + sr) * ldb + skf;
    int sd = wid * 1024;

    int nk = K >> 6;

    auto stage = [&](int half, int tt, int d) {
        int kt = tt < nk ? tt : nk - 1;
        const u16* s = (half < 2 ? gA + (size_t)(half * 128) * lda
                                 : gB + (size_t)((half - 2) * 128) * ldb) + kt * 64;
        size_t ld = (half < 2) ? (size_t)lda : (size_t)ldb;
        glds16(s, &lds[d][half][sd]);
        glds16(s + 8 * ld, &lds[d][half][sd + 512]);
    };

    f32x4 acc[8][4];
    #pragma unroll
    for (int i = 0; i < 8; i++)
        #pragma unroll
        for (int j = 0; j < 4; j++) { f32x4 zz = {0.f, 0.f, 0.f, 0.f}; acc[i][j] = zz; }

    int ha = wid >> 2;
    int hb = (wid >> 1) & 1;
    int vb0 = lr * 64 + (((q + lr) & 7) << 3);
    int vb1 = lr * 64 + (((4 + q + lr) & 7) << 3);
    int bb = (wid & 1) * 4096;

    stage(0, 0, 0); stage(1, 0, 0); stage(2, 0, 0); stage(3, 0, 0);
    stage(2, 1, 1); stage(0, 1, 1);
    asm volatile("s_waitcnt vmcnt(4)" ::: "memory");
    asm volatile("s_barrier" ::: "memory");

    s16x8 a[4][2], b0[2][2], b1[2][2];

    for (int tt = 0; tt < nk; ++tt) {
        int cur = tt & 1, nxt = cur ^ 1;
        const u16* Ah = &lds[cur][ha][0];
        const u16* Bh = &lds[cur][2 + hb][bb];

        #pragma unroll
        for (int i = 0; i < 4; i++) {
            a[i][0] = *(const s16x8*)&Ah[vb0 + i * 1024];
            a[i][1] = *(const s16x8*)&Ah[vb1 + i * 1024];
        }
        #pragma unroll
        for (int j = 0; j < 2; j++) {
            b0[j][0] = *(const s16x8*)&Bh[vb0 + j * 1024];
            b0[j][1] = *(const s16x8*)&Bh[vb1 + j * 1024];
        }
        stage(1, tt + 1, nxt);
        asm volatile("s_barrier" ::: "memory");
        asm volatile("s_waitcnt lgkmcnt(0)" ::: "memory");
        __builtin_amdgcn_s_setprio(1);
        #pragma unroll
        for (int i = 0; i < 4; i++)
            #pragma unroll
            for (int j = 0; j < 2; j++) {
                acc[i][j] = __builtin_amdgcn_mfma_f32_16x16x32_bf16(a[i][0], b0[j][0], acc[i][j], 0, 0, 0);
                acc[i][j] = __builtin_amdgcn_mfma_f32_16x16x32_bf16(a[i][1], b0[j][1], acc[i][j], 0, 0, 0);
            }
        __builtin_amdgcn_s_setprio(0);
        asm volatile("s_barrier" ::: "memory");

        #pragma unroll
        for (int j = 0; j < 2; j++) {
            b1[j][0] = *(const s16x8*)&Bh[2048 + vb0 + j * 1024];
            b1[j][1] = *(const s16x8*)&Bh[2048 + vb1 + j * 1024];
        }
        stage(3, tt + 1, nxt);
        asm volatile("s_barrier" ::: "memory");
        asm volatile("s_waitcnt lgkmcnt(0)" ::: "memory");
        __builtin_amdgcn_s_setprio(1);
        #pragma unroll
        for (int i = 0; i < 4; i++)
            #pragma unroll
            for (int j = 0; j < 2; j++) {
                acc[i][2 + j] = __builtin_amdgcn_mfma_f32_16x16x32_bf16(a[i][0], b1[j][0], acc[i][2 + j], 0, 0, 0);
                acc[i][2 + j] = __builtin_amdgcn_mfma_f32_16x16x32_bf16(a[i][1], b1[j][1], acc[i][2 + j], 0, 0, 0);
            }
        __builtin_amdgcn_s_setprio(0);
        asm volatile("s_barrier" ::: "memory");

        #pragma unroll
        for (int i = 0; i < 4; i++) {
            a[i][0] = *(const s16x8*)&Ah[4096 + vb0 + i * 1024];
            a[i][1] = *(const s16x8*)&Ah[4096 + vb1 + i * 1024];
        }
        stage(2, tt + 2, cur);
        asm volatile("s_barrier" ::: "memory");
        asm volatile("s_waitcnt lgkmcnt(0)" ::: "memory");
        __builtin_amdgcn_s_setprio(1);
        #pragma unroll
        for (int i = 0; i < 4; i++)
            #pragma unroll
            for (int j = 0; j < 2; j++) {
                acc[4 + i][2 + j] = __builtin_amdgcn_mfma_f32_16x16x32_bf16(a[i][0], b1[j][0], acc[4 + i][2 + j], 0, 0, 0);
                acc[4 + i][2 + j] = __builtin_amdgcn_mfma_f32_16x16x32_bf16(a[i][1], b1[j][1], acc[4 + i][2 + j], 0, 0, 0);
            }
        __builtin_amdgcn_s_setprio(0);
        asm volatile("s_barrier" ::: "memory");

        stage(0, tt + 2, cur);
        asm volatile("s_barrier" ::: "memory");
        __builtin_amdgcn_s_setprio(1);
        #pragma unroll
        for (int i = 0; i < 4; i++)
            #pragma unroll
            for (int j = 0; j < 2; j++) {
                acc[4 + i][j] = __builtin_amdgcn_mfma_f32_16x16x32_bf16(a[i][0], b0[j][0], acc[4 + i][j], 0, 0, 0);
                acc[4 + i][j] = __builtin_amdgcn_mfma_f32_16x16x32_bf16(a[i][1], b0[j][1], acc[4 + i][j], 0, 0, 0);
            }
        __builtin_amdgcn_s_setprio(0);
        asm volatile("s_waitcnt vmcnt(4)" ::: "memory");
        asm volatile("s_barrier" ::: "memory");
    }

    asm volatile("s_waitcnt vmcnt(0)" ::: "memory");

    int wm = (wid >> 2) * 128, wn = (wid & 3) * 64;
    #pragma unroll
    for (int mi = 0; mi < 8; mi++) {
        #pragma unroll
        for (int r = 0; r < 4; r++) {
            int row = m0 + wm + mi * 16 + q * 4 + r;
            #pragma unroll
            for (int nj = 0; nj < 4; nj++) {
                int col = n0 + wn + nj * 16 + lr;
                float v = acc[mi][nj][r] + bias[col];
                if (EPI == EPI_QKV) {
                    if (n0 + wn + nj * 16 < 4096) v = (v > 0.f) ? (v + 1.f) : __expf(v);
                } else {  // EPI_GELU
                    float u = v * (0.7978845608f + 0.0356774081f * v * v);
                    u = fminf(u, 40.f);
                    float e = __expf(2.f * u);
                    v = v * __fdividef(e, e + 1.f);
                }
                C[(size_t)row * N + col] = f2bf(v);
            }
        }
    }
}

// ---------------- GEMM NT 128x256, 8-wave, TRIPLE-buffered, 2-phase counted vmcnt ----------------
// LDS: 3 bufs x (A 128x64 + B 256x64) bf16 = 3 x 48KB = 144KB -> 1 block/CU.
// Wave tile 64x64 (2M x 4N waves). Per K-tile: 2 phases x 16 MFMA, 4 barriers.
// Staging for tile t+2 issued during tile t (3-buffer -> no write-after-read
// hazard: write target is always 2 tiles ahead of the read buffer).
// vmcnt(6) at tile end: outstanding = t+1's 6 instrs + t+2's 6 -> drains t+1
// exactly; full-K-tile latency window (~1300 clk) covers LLC latency.
// Grid MUST be (N/256, M/128) with gridDim.x%4==0, gridDim.y%2==0.
template <int EPI>
__global__ __launch_bounds__(512, 2) void gemm3b(
    const u16* __restrict__ A, const u16* __restrict__ B, u16* __restrict__ C,
    const float* __restrict__ bias, int M, int N, int K, int lda, int ldb) {

    __shared__ __align__(16) u16 lds[3][24576];  // per buf: A[0..8191], B[8192..24575]

    int p = blockIdx.y * gridDim.x + blockIdx.x;
    int g = p & 7, rr = p >> 3;
    int lw = gridDim.x >> 2, lh = gridDim.y >> 1;
    int ly = rr / lw, lx = rr - ly * lw;
    int m0 = ((g >> 2) * lh + ly) * 128;
    int n0 = ((g & 3) * lw + lx) * 256;

    int t = threadIdx.x;
    int lane = t & 63, wid = t >> 6;
    int lr = lane & 15, q = lane >> 4;

    // staging addresses (pre-swizzled source chunk)
    int skf = (((lane & 7) - (lane >> 3)) & 7) * 8;
    const u16* gA = A + (size_t)(m0 + wid * 16 + (lane >> 3)) * lda + skf;
    const u16* gB = B + (size_t)(n0 + wid * 32 + (lane >> 3)) * ldb + skf;
    int sdA = wid * 1024;   // wave's 16 A-rows
    int sdB = 8192 + wid * 2048;  // wave's 32 B-rows

    int nk = K >> 6;

    auto stageA = [&](int tt, int d) {
        int kt = (tt < nk ? tt : nk - 1) << 6;
        glds16(gA + kt, &lds[d][sdA]);
        glds16(gA + kt + (size_t)8 * lda, &lds[d][sdA + 512]);
    };
    auto stageB = [&](int tt, int d) {
        int kt = (tt < nk ? tt : nk - 1) << 6;
        #pragma unroll
        for (int r2 = 0; r2 < 4; ++r2)
            glds16(gB + kt + (size_t)(8 * r2) * ldb, &lds[d][sdB + r2 * 512]);
    };

    f32x4 acc[4][4];
    #pragma unroll
    for (int i = 0; i < 4; i++)
        #pragma unroll
        for (int j = 0; j < 4; j++) { f32x4 zz = {0.f, 0.f, 0.f, 0.f}; acc[i][j] = zz; }

    int wm = (wid >> 2) * 64, wn = (wid & 3) * 64;
    // fragment LDS offsets (u16 units); row&7 == lr&7 for all frag rows
    int aoff0 = wm * 64 + lr * 64 + (((q + lr) & 7) << 3);        // kk=0
    int aoff1 = wm * 64 + lr * 64 + (((4 + q + lr) & 7) << 3);    // kk=1
    int boff0 = 8192 + wn * 64 + lr * 64 + (((q + lr) & 7) << 3);
    int boff1 = 8192 + wn * 64 + lr * 64 + (((4 + q + lr) & 7) << 3);

    // ---- prologue: tiles 0,1 staged ----
    stageA(0, 0); stageB(0, 0);
    stageA(1, 1); stageB(1, 1);
    asm volatile("s_waitcnt vmcnt(6)" ::: "memory");  // tile 0 landed
    asm volatile("s_barrier" ::: "memory");

    s16x8 a[4][2], b[4][2];

    for (int tt = 0; tt < nk; ++tt) {
        int cur = tt % 3, nx2 = (tt + 2) % 3;
        const u16* L = &lds[cur][0];

        // ---- phase 1: ds A(all) + B(j=0,1) | stage B(t+2) | mfma j=0,1 ----
        #pragma unroll
        for (int i = 0; i < 4; i++) {
            a[i][0] = *(const s16x8*)&L[aoff0 + i * 1024];
            a[i][1] = *(const s16x8*)&L[aoff1 + i * 1024];
        }
        #pragma unroll
        for (int j = 0; j < 2; j++) {
            b[j][0] = *(const s16x8*)&L[boff0 + j * 1024];
            b[j][1] = *(const s16x8*)&L[boff1 + j * 1024];
        }
        stageB(tt + 2, nx2);
        asm volatile("s_barrier" ::: "memory");
        asm volatile("s_waitcnt lgkmcnt(0)" ::: "memory");
        __builtin_amdgcn_s_setprio(1);
        #pragma unroll
        for (int i = 0; i < 4; i++)
            #pragma unroll
            for (int j = 0; j < 2; j++) {
                acc[i][j] = __builtin_amdgcn_mfma_f32_16x16x32_bf16(a[i][0], b[j][0], acc[i][j], 0, 0, 0);
                acc[i][j] = __builtin_amdgcn_mfma_f32_16x16x32_bf16(a[i][1], b[j][1], acc[i][j], 0, 0, 0);
            }
        __builtin_amdgcn_s_setprio(0);
        asm volatile("s_barrier" ::: "memory");

        // ---- phase 2: ds B(j=2,3) | stage A(t+2) | mfma j=2,3 | vmcnt(6) ----
        #pragma unroll
        for (int j = 2; j < 4; j++) {
            b[j][0] = *(const s16x8*)&L[boff0 + j * 1024];
            b[j][1] = *(const s16x8*)&L[boff1 + j * 1024];
        }
        stageA(tt + 2, nx2);
        asm volatile("s_barrier" ::: "memory");
        asm volatile("s_waitcnt lgkmcnt(0)" ::: "memory");
        __builtin_amdgcn_s_setprio(1);
        #pragma unroll
        for (int i = 0; i < 4; i++)
            #pragma unroll
            for (int j = 2; j < 4; j++) {
                acc[i][j] = __builtin_amdgcn_mfma_f32_16x16x32_bf16(a[i][0], b[j][0], acc[i][j], 0, 0, 0);
                acc[i][j] = __builtin_amdgcn_mfma_f32_16x16x32_bf16(a[i][1], b[j][1], acc[i][j], 0, 0, 0);
            }
        __builtin_amdgcn_s_setprio(0);
        asm volatile("s_waitcnt vmcnt(6)" ::: "memory");  // t+1 fully landed; never 0
        asm volatile("s_barrier" ::: "memory");
    }

    // ---- epilogue ----
    #pragma unroll
    for (int i = 0; i < 4; i++) {
        #pragma unroll
        for (int r = 0; r < 4; r++) {
            int row = m0 + wm + i * 16 + q * 4 + r;
            #pragma unroll
            for (int j = 0; j < 4; j++) {
                int col = n0 + wn + j * 16 + lr;
                float v = acc[i][j][r] + bias[col];
                if (EPI == EPI_QKV) {
                    if (n0 + wn + j * 16 < 4096) v = (v > 0.f) ? (v + 1.f) : __expf(v);  // elu+1
                } else {  // EPI_GELU
                    float u = v * (0.7978845608f + 0.0356774081f * v * v);
                    u = fminf(u, 40.f);
                    float e = __expf(2.f * u);
                    v = v * __fdividef(e, e + 1.f);
                }
                C[(size_t)row * N + col] = f2bf(v);
            }
        }
    }
    asm volatile("s_waitcnt vmcnt(0)" ::: "memory");  // drain DMA before exit
}

extern "C" void kernel_launch(void* const* d_in, const int* in_sizes, int n_in,
                              void* d_out, int out_size, void* d_ws, size_t ws_size,
                              hipStream_t stream) {
    const float* x    = (const float*)d_in[0];
    const float* q_w  = (const float*)d_in[1];
    const float* q_b  = (const float*)d_in[2];
    const float* k_w  = (const float*)d_in[3];
    const float* k_b  = (const float*)d_in[4];
    const float* v_w  = (const float*)d_in[5];
    const float* v_b  = (const float*)d_in[6];
    const float* o_w  = (const float*)d_in[7];
    const float* o_b  = (const float*)d_in[8];
    const float* ln1g = (const float*)d_in[9];
    const float* ln1b = (const float*)d_in[10];
    const float* ln2g = (const float*)d_in[11];
    const float* ln2b = (const float*)d_in[12];
    const float* w1   = (const float*)d_in[13];
    const float* b1   = (const float*)d_in[14];
    const float* w2   = (const float*)d_in[15];
    const float* b2   = (const float*)d_in[16];
    float* out = (float*)d_out;

    constexpr int Bb = 2, N = 2048, D = 1024, E = 2048, F = 4096;
    constexpr int BN = Bb * N;     // 4096
    constexpr int E3 = 3 * E;      // 6144

    char* ws = (char*)d_ws;
    size_t off = 0;
    auto alloc = [&](size_t bytes) -> void* {
        void* p = ws + off;
        off += (bytes + 255) & ~(size_t)255;
        return p;
    };
    u16*   qkvT = (u16*)alloc((size_t)E3 * D * 2);     // 12 MB
    u16*   oT   = (u16*)alloc((size_t)D * E * 2);      // 4 MB
    u16*   w1T  = (u16*)alloc((size_t)F * D * 2);      // 8 MB
    u16*   w2T  = (u16*)alloc((size_t)D * F * 2);      // 8 MB
    float* bcat = (float*)alloc((size_t)E3 * 4);
    u16*   xn   = (u16*)alloc((size_t)BN * D * 2);     // 8 MB (reused as xn2)
    u16*   QKV  = (u16*)alloc((size_t)BN * E3 * 2);    // 48 MB (reused: P, h)
    u16*   Vt   = (u16*)alloc((size_t)Bb * E * N * 2); // 16 MB (reused as x2 fp32)
    u16*   Amat = (u16*)alloc((size_t)Bb * N * N * 2); // 32 MB (reused as parts)
    float* den  = (float*)alloc((size_t)BN * 4);

    u16*   xn2 = xn;
    u16*   P   = QKV;                  // [BN,E] bf16
    u16*   h   = QKV + (size_t)8 * 1024 * 1024;  // [BN,F] bf16
    float* x2  = (float*)Vt;           // [BN,D] fp32
    float* pt0 = (float*)Amat;         // split-K partial 0
    float* pt1 = pt0 + (size_t)BN * D; // split-K partial 1

    dim3 blk(256);

    // ---- prep: biases + den zero ----
    prep<<<dim3((BN + 255) / 256), blk, 0, stream>>>(q_b, k_b, v_b, bcat, den, E, BN);

    // ---- all weight transposes, one dispatch ----
    transpose_all<<<dim3(4096, 6), blk, 0, stream>>>(
        q_w, k_w, v_w, o_w, w1, w2, qkvT, oT, w1T, w2T);

    // ---- LN1 ----
    ln_bf16<<<BN, blk, 0, stream>>>(x, ln1g, ln1b, xn, D);

    // ---- fused QKV projection: [BN,3E], elu+1 on Q,K cols (128x256 3-buf) ----
    gemm3b<EPI_QKV><<<dim3(E3 / 256, BN / 128), dim3(512), 0, stream>>>(
        xn, qkvT, QKV, bcat, BN, E3, D, D, D);

    // ---- V^T per batch: [N,E] (stride 3E) -> [E,N] ----
    transpose_u16<<<dim3(E / 32, N / 32, Bb), blk, 0, stream>>>(
        QKV + 2 * E, Vt, N, E, E3, (ll)N * E3, (ll)E * N);

    // ---- A = tril(Q K^T) per batch, fused rowsum -> den (BK=64) ----
    gemm_nt<EPI_TRIL, 64><<<dim3(N / 128, N / 128, Bb), blk, 0, stream>>>(
        QKV, QKV + E, Amat, nullptr, den, N, N, E, E3, E3,
        (ll)N * E3, (ll)N * E3, (ll)N * N, (ll)N);

    // ---- P = (A @ V) / den (triangular K-loop, BK=64) ----
    gemm_nt<EPI_DIV, 64><<<dim3(E / 128, N / 128, Bb), blk, 0, stream>>>(
        Amat, Vt, P, nullptr, den, N, E, N, N, N,
        (ll)N * N, (ll)E * N, (ll)N * E, (ll)N);

    // ---- split-K=2: parts = P @ o_w (fp32), BK=64 ----
    gemm_nt<EPI_PART, 64><<<dim3(D / 128, BN / 128, 2), blk, 0, stream>>>(
        P, oT, pt0, nullptr, nullptr, BN, D, E / 2, E, E,
        (ll)(E / 2), (ll)(E / 2), (ll)BN * D, 0);

    // ---- x2 = x + p0 + p1 + o_b ; xn2 = LN2(x2) ----
    combine_ln<<<BN, blk, 0, stream>>>(x, pt0, pt1, o_b, ln2g, ln2b, x2, xn2);

    // ---- h = gelu(xn2 @ w1 + b1) (256^2 4-phase, A/B reference) ----
    gemm_nt256<EPI_GELU><<<dim3(F / 256, BN / 256), dim3(512), 0, stream>>>(
        xn2, w1T, h, b1, BN, F, D, D, D);

    // ---- split-K=2: parts = h @ w2 (fp32), BK=64 ----
    gemm_nt<EPI_PART, 64><<<dim3(D / 128, BN / 128, 2), blk, 0, stream>>>(
        h, w2T, pt0, nullptr, nullptr, BN, D, F / 2, F, F,
        (ll)(F / 2), (ll)(F / 2), (ll)BN * D, 0);

    // ---- out = x2 + p0 + p1 + b2 ----
    combine_out<<<dim3(BN * D / 4 / 256), blk, 0, stream>>>(x2, pt0, pt1, b2, out);
}